// Round 9
// baseline (57.494 us; speedup 1.0000x reference)
//
#include <hip/hip_runtime.h>

// Linear attention (chunked cumulative state), B=4 H=8 N=4096 D=E=64 CHUNK=128.
// phase1: per-chunk K^T V via bf16 MFMA + fp32 k-colsums. Relays bf16 K (row-major)
//         and V (subtiled) to workspace for phase3.
// phase2: register prefix scan over chunks (fp32 accum, bf16 prefixes, fp32 tails).
// phase3: per-chunk output via bf16 MFMA. K A-frags + state B-frags read directly
//         from global (L1/L2-resident bf16 relays); V staged via pure 16B copies;
//         no s_lds zero-init (inline zero tiles); LDS 49KB -> 3 blocks/CU.

#define CHUNKSZ 128
#define DD 64
#define EE 64
#define NC 32          // N / CHUNK
#define NBH 32         // B*H
#define NSEQ 4096
#define EPSV 1e-6f
#define OUT0 (NBH * NSEQ * EE)           // start of Z output
#define KV_ELEMS (NBH * NC * DD * EE)    // ushort count (states)

typedef short bf16x8 __attribute__((ext_vector_type(8)));
typedef short bf16x4 __attribute__((ext_vector_type(4)));
typedef float f32x4  __attribute__((ext_vector_type(4)));

__device__ __forceinline__ unsigned short f2bf(float f) {
    union { float f; unsigned u; } x; x.f = f;
    unsigned u = x.u + 0x7FFFu + ((x.u >> 16) & 1u);   // RNE
    return (unsigned short)(u >> 16);
}
__device__ __forceinline__ float bf2f(unsigned short s) {
    union { unsigned u; float f; } x; x.u = ((unsigned)s) << 16;
    return x.f;
}

// ---------------- phase 1: kvT[e][d] = sum_m K[m][d] V[m][e]  (bf16) ----------------
// kT/vT LDS layout: byte(m,col) = (m>>3)*1024 + col*16 + (m&7)*2
__global__ __launch_bounds__(256) void la_phase1(
    const float* __restrict__ k, const float* __restrict__ v,
    unsigned short* __restrict__ kvT, float* __restrict__ ks,
    unsigned short* __restrict__ krel, unsigned short* __restrict__ vrel)
{
    const int phys = blockIdx.x;
    const int blk  = (phys & 7) * 128 + (phys >> 3);   // XCD-contiguous logical id
    const int bh = blk >> 5, c = blk & 31;
    const size_t rowbase = (size_t)bh * NSEQ + (size_t)c * CHUNKSZ;

    __shared__ alignas(16) unsigned short kT[CHUNKSZ * DD];
    __shared__ alignas(16) unsigned short vT[CHUNKSZ * EE];
    __shared__ float ksp[4][DD];

    char* kb = (char*)kT;
    char* vb = (char*)vT;

    const int t = threadIdx.x;
    const int w = t >> 6, l = t & 63;
    const int lg = l >> 4, lm = l & 15;
    const int col = t & 63;

    unsigned short* krc = krel + (size_t)(bh * NC + c) * (CHUNKSZ * DD);
    unsigned short* vrc = vrel + (size_t)(bh * NC + c) * (CHUNKSZ * EE);

    // column-pack staging: thread owns column `col`, m-groups w, w+4, w+8, w+12.
    // Also emits bf16 relays: K row-major (scalar, per-j wave-contiguous 128B),
    // V subtiled (16B vector, wave-contiguous 1KB).
    float kpart = 0.f;
#pragma unroll
    for (int pass = 0; pass < 4; ++pass) {
        const int mg = w + 4 * pass;
        const float* kp = k + (rowbase + mg * 8) * DD + col;
        const float* vp = v + (rowbase + mg * 8) * EE + col;
        float kf[8], vf[8];
#pragma unroll
        for (int j = 0; j < 8; ++j) kf[j] = kp[(size_t)j * DD];
#pragma unroll
        for (int j = 0; j < 8; ++j) vf[j] = vp[(size_t)j * EE];
        bf16x8 ku, vu;
#pragma unroll
        for (int j = 0; j < 8; ++j) {
            kpart += kf[j];
            ku[j] = (short)f2bf(kf[j]);
            vu[j] = (short)f2bf(vf[j]);
        }
        *(bf16x8*)(kb + mg * 1024 + col * 16) = ku;
        *(bf16x8*)(vb + mg * 1024 + col * 16) = vu;
#pragma unroll
        for (int j = 0; j < 8; ++j)
            krc[(size_t)(mg * 8 + j) * DD + col] = (unsigned short)ku[j];
        *(bf16x8*)(vrc + mg * 512 + col * 8) = vu;
    }
    ksp[w][col] = kpart;
    __syncthreads();

    // MFMA: wave w owns d-tile w, all 4 e-tiles, K=128 in 4 steps.
    f32x4 acc[4] = {};
#pragma unroll
    for (int kk = 0; kk < 4; ++kk) {
        bf16x8 aK = *(bf16x8*)(kb + (lg + 4 * kk) * 1024 + (16 * w + lm) * 16);
#pragma unroll
        for (int ei = 0; ei < 4; ++ei) {
            bf16x8 bV = *(bf16x8*)(vb + (lg + 4 * kk) * 1024 + (16 * ei + lm) * 16);
            acc[ei] = __builtin_amdgcn_mfma_f32_16x16x32_bf16(aK, bV, acc[ei], 0, 0, 0);
        }
    }
    // C-frag: row d = 16w+4lg+r, col e = 16ei+lm -> store transposed [e][d] bf16
    unsigned short* kvout = kvT + (size_t)(bh * NC + c) * DD * EE;
#pragma unroll
    for (int ei = 0; ei < 4; ++ei) {
        bf16x4 u;
        u[0] = (short)f2bf(acc[ei][0]); u[1] = (short)f2bf(acc[ei][1]);
        u[2] = (short)f2bf(acc[ei][2]); u[3] = (short)f2bf(acc[ei][3]);
        *(bf16x4*)(kvout + (16 * ei + lm) * DD + 16 * w + 4 * lg) = u;
    }
    if (t < DD)
        ks[(size_t)(bh * NC + c) * DD + t] = ksp[0][t] + ksp[1][t] + ksp[2][t] + ksp[3][t];
}

// ---------------- phase 2: exclusive prefix scan over chunks ----------------
__global__ __launch_bounds__(64) void la_phase2(
    unsigned short* __restrict__ kvT, float* __restrict__ ks, float* __restrict__ out)
{
    const int bid = blockIdx.x, t = threadIdx.x;
    if (bid < 256) {
        const int gid = bid * 64 + t;            // 0..16383
        const int bh = gid >> 9;
        const int g = gid & 511;                 // group of 8 ushorts in [e][d] tile
        unsigned short* base = kvT + (size_t)bh * (NC * DD * EE) + (size_t)g * 8;
        bf16x8 vals[NC];
#pragma unroll
        for (int c = 0; c < NC; ++c)
            vals[c] = *(const bf16x8*)(base + (size_t)c * (DD * EE));
        float run[8] = {};
#pragma unroll
        for (int c = 0; c < NC; ++c) {
            bf16x8 pr;
#pragma unroll
            for (int j = 0; j < 8; ++j) pr[j] = (short)f2bf(run[j]);
            *(bf16x8*)(base + (size_t)c * (DD * EE)) = pr;
#pragma unroll
            for (int j = 0; j < 8; ++j) run[j] += bf2f((unsigned short)vals[c][j]);
        }
        // S tail (fp32, [d][e] layout): g = e*8 + d0/8
        const int e = g >> 3, d0 = (g & 7) * 8;
        float* Sout = out + OUT0 + NBH * DD + (size_t)bh * DD * EE;
#pragma unroll
        for (int j = 0; j < 8; ++j)
            Sout[(size_t)(d0 + j) * EE + e] = run[j];
    } else {
        const int tid = (bid - 256) * 64 + t;    // 0..2047 = bh*64 + d
        const int bh = tid >> 6, d = tid & 63;
        float vals[NC];
#pragma unroll
        for (int c = 0; c < NC; ++c)
            vals[c] = ks[(size_t)(bh * NC + c) * DD + d];
        float run = 0.f;
#pragma unroll
        for (int c = 0; c < NC; ++c) {
            float x = vals[c];
            ks[(size_t)(bh * NC + c) * DD + d] = run;
            run += x;
        }
        out[OUT0 + tid] = run;                   // Z tail
    }
}

// ---------------- phase 3: per-chunk output via MFMA ----------------
// s_lds row-major [n][m] swizzled: byte(n,m) = n*256 + ((m*2) ^ ((n&7)<<4))
// v_lds subtiled:  byte(m,e) = (m>>3)*1024 + e*16 + (m&7)*2
// K A-frags and state B-frags read directly from global bf16 (L1/L2 resident).
// wave w owns row-tiles ni = w and ni = 7-w (balanced causal work).
__global__ __launch_bounds__(256) void la_phase3(
    const float* __restrict__ q, const unsigned short* __restrict__ krel,
    const unsigned short* __restrict__ vrel, const unsigned short* __restrict__ kvT,
    const float* __restrict__ ks, float* __restrict__ out)
{
    const int phys = blockIdx.x;
    const int blk  = (phys & 7) * 128 + (phys >> 3);   // XCD-contiguous logical id
    const int bh = blk >> 5, c = blk & 31;
    const size_t rowbase = (size_t)bh * NSEQ + (size_t)c * CHUNKSZ;

    __shared__ alignas(16) unsigned short v_lds[CHUNKSZ * EE];
    __shared__ alignas(16) unsigned short s_lds[CHUNKSZ * CHUNKSZ];
    __shared__ float dinv_lds[CHUNKSZ];
    __shared__ float zi_lds[DD];

    char* vb = (char*)v_lds;
    char* sb = (char*)s_lds;

    const int t  = threadIdx.x;
    const int w  = t >> 6;
    const int l  = t & 63;
    const int lg = l >> 4;
    const int lm = l & 15;
    const int ni_of[2] = { w, 7 - w };

    const unsigned short* krc = krel + (size_t)(bh * NC + c) * (CHUNKSZ * DD);
    const unsigned short* vrc = vrel + (size_t)(bh * NC + c) * (CHUNKSZ * EE);
    const unsigned short* stc = kvT + (size_t)(bh * NC + c) * DD * EE;

    // ---- staging ----
    // V: pure 16B copy (subtiled relay -> subtiled LDS), conflict-free
#pragma unroll
    for (int i = 0; i < 4; ++i) {
        int idx = t + 256 * i;                  // 0..1023 16B chunks
        *(bf16x8*)(vb + idx * 16) = *(const bf16x8*)(vrc + (size_t)idx * 8);
    }
    // Z exclusive prefix for this chunk
    if (t < DD) zi_lds[t] = ks[(size_t)(bh * NC + c) * DD + t];

    // state B-frags direct from global (exclusive prefix, [e][d] row-major)
    bf16x8 b_st[4][2];
#pragma unroll
    for (int ei = 0; ei < 4; ++ei)
#pragma unroll
        for (int kk = 0; kk < 2; ++kk)
            b_st[ei][kk] = *(const bf16x8*)(stc + (size_t)(16 * ei + lm) * DD + 8 * lg + 32 * kk);

    // Q A-fragments: a_q[ni2][kk], row n = 16*ni + lm, d = 8*lg + 32*kk + i
    bf16x8 a_q[2][2];
#pragma unroll
    for (int ni2 = 0; ni2 < 2; ++ni2) {
        int ni = ni_of[ni2];
        const float* qrow = q + (rowbase + 16 * ni + lm) * DD;
#pragma unroll
        for (int kk = 0; kk < 2; ++kk) {
            const float4* p = (const float4*)(qrow + 8 * lg + 32 * kk);
            float4 f0 = p[0], f1 = p[1];
            bf16x8 u;
            u[0] = (short)f2bf(f0.x); u[1] = (short)f2bf(f0.y);
            u[2] = (short)f2bf(f0.z); u[3] = (short)f2bf(f0.w);
            u[4] = (short)f2bf(f1.x); u[5] = (short)f2bf(f1.y);
            u[6] = (short)f2bf(f1.z); u[7] = (short)f2bf(f1.w);
            a_q[ni2][kk] = u;
        }
    }
    __syncthreads();

    // ---- swapped QK^T -> masked S (bf16, vector writes) + in-fragment denominator ----
    // K A-frags loaded directly from bf16 row-major relay (16KB, L1-resident).
#pragma unroll
    for (int ni2 = 0; ni2 < 2; ++ni2) {
        const int ni = ni_of[ni2];
        const int n = 16 * ni + lm;
        float rsum = 0.f;
        for (int mi = 0; mi <= ni; ++mi) {
            f32x4 cc = {0.f, 0.f, 0.f, 0.f};
            const int mrow = 16 * mi + lm;
#pragma unroll
            for (int kk = 0; kk < 2; ++kk) {
                bf16x8 ak = *(const bf16x8*)(krc + (size_t)mrow * DD + 8 * lg + 32 * kk);
                // C[m-local = 4lg+r][n-local = lm]
                cc = __builtin_amdgcn_mfma_f32_16x16x32_bf16(ak, a_q[ni2][kk], cc, 0, 0, 0);
            }
            const int m0 = 16 * mi + 4 * lg;
            bf16x4 u;
#pragma unroll
            for (int r = 0; r < 4; ++r) {
                float val = (m0 + r <= n) ? cc[r] : 0.f;   // causal mask
                u[r] = (short)f2bf(val);
                rsum += val;
            }
            *(bf16x4*)(sb + n * 256 + ((m0 * 2) ^ ((n & 7) << 4))) = u;
        }
        if ((ni & 1) == 0) {                     // zero tile mi = ni+1 (read by SV)
            bf16x4 z4 = {0, 0, 0, 0};
            const int m0 = 16 * (ni + 1) + 4 * lg;
            *(bf16x4*)(sb + n * 256 + ((m0 * 2) ^ ((n & 7) << 4))) = z4;
        }
        // q . Z_prefix + eps * sum(q) for row n (from bf16 Q frags)
        float qz = 0.f, qs = 0.f;
#pragma unroll
        for (int kk = 0; kk < 2; ++kk) {
#pragma unroll
            for (int i = 0; i < 8; ++i) {
                float qf = bf2f((unsigned short)a_q[ni2][kk][i]);
                qz += qf * zi_lds[8 * lg + 32 * kk + i];
                qs += qf;
            }
        }
        float part = rsum + qz + EPSV * qs;
        part += __shfl_xor(part, 16);
        part += __shfl_xor(part, 32);
        if (lg == 0) dinv_lds[n] = 1.f / part;
    }
    __syncthreads();

    // ---- O = Q*S_state + S*V ----
    f32x4 acc[2][4];
#pragma unroll
    for (int ni2 = 0; ni2 < 2; ++ni2) {
        const int ni = ni_of[ni2];
        const int kmax = (ni >> 1) + 1;
#pragma unroll
        for (int ei = 0; ei < 4; ++ei) {
            f32x4 cc = {0.f, 0.f, 0.f, 0.f};
            const int e = 16 * ei + lm;
#pragma unroll
            for (int kk = 0; kk < 2; ++kk)   // inter: Q x S_state (B-frags in regs)
                cc = __builtin_amdgcn_mfma_f32_16x16x32_bf16(a_q[ni2][kk], b_st[ei][kk], cc, 0, 0, 0);
            const int n = 16 * ni + lm;
            for (int kk = 0; kk < kmax; ++kk) {   // intra: S x V
                int bytA = n * 256 + (((8 * lg + 32 * kk) * 2) ^ ((n & 7) << 4));
                bf16x8 as = *(bf16x8*)(sb + bytA);
                int bytB = (lg + 4 * kk) * 1024 + e * 16;
                bf16x8 bv = *(bf16x8*)(vb + bytB);
                cc = __builtin_amdgcn_mfma_f32_16x16x32_bf16(as, bv, cc, 0, 0, 0);
            }
            acc[ni2][ei] = cc;
        }
    }
    __syncthreads();

    // ---- epilogue: scale by dinv, store ----
#pragma unroll
    for (int ni2 = 0; ni2 < 2; ++ni2) {
        const int nbase = 16 * ni_of[ni2] + 4 * lg;
#pragma unroll
        for (int ei = 0; ei < 4; ++ei) {
            const int e = 16 * ei + lm;
#pragma unroll
            for (int r = 0; r < 4; ++r) {
                int n = nbase + r;
                out[(rowbase + n) * EE + e] = acc[ni2][ei][r] * dinv_lds[n];
            }
        }
    }
}

extern "C" void kernel_launch(void* const* d_in, const int* in_sizes, int n_in,
                              void* d_out, int out_size, void* d_ws, size_t ws_size,
                              hipStream_t stream)
{
    (void)in_sizes; (void)n_in; (void)out_size; (void)ws_size;
    const float* q = (const float*)d_in[0];
    const float* k = (const float*)d_in[1];
    const float* v = (const float*)d_in[2];
    float* out = (float*)d_out;
    unsigned short* kvT = (unsigned short*)d_ws;            // 8 MB bf16 per-chunk states
    float* ks = (float*)(kvT + KV_ELEMS);                   // +256 KB fp32 per-chunk k-sums
    unsigned short* krel = (unsigned short*)(ks + NBH * NC * DD);  // 16 MB bf16 K (row-major)
    unsigned short* vrel = krel + (size_t)NBH * NSEQ * DD;         // 16 MB bf16 V (subtiled)

    la_phase1<<<NBH * NC, 256, 0, stream>>>(k, v, kvT, ks, krel, vrel);
    la_phase2<<<288, 64, 0, stream>>>(kvT, ks, out);
    la_phase3<<<NBH * NC, 256, 0, stream>>>(q, krel, vrel, kvT, ks, out);
}

// Round 10
// 51.368 us; speedup vs baseline: 1.1193x; 1.1193x over previous
//
#include <hip/hip_runtime.h>

// Linear attention (chunked cumulative state), B=4 H=8 N=4096 D=E=64 CHUNK=128.
// phase1: per-chunk K^T V via bf16 MFMA + fp32 k-colsums (column-pack staging).
// phase2: register prefix scan over chunks (fp32 accum, bf16 prefixes, fp32 tails).
// phase3: per-chunk output via bf16 MFMA. Swapped QK^T, in-fragment denominator,
//         {w,7-w} wave balance, NO s_lds zero-init (inline zero tiles), state
//         B-frags direct from global (L2/L3-warm kvT) -- no st_lds.

#define CHUNKSZ 128
#define DD 64
#define EE 64
#define NC 32          // N / CHUNK
#define NBH 32         // B*H
#define NSEQ 4096
#define EPSV 1e-6f
#define OUT0 (NBH * NSEQ * EE)           // start of Z output
#define KV_ELEMS (NBH * NC * DD * EE)    // ushort count

typedef short bf16x8 __attribute__((ext_vector_type(8)));
typedef short bf16x4 __attribute__((ext_vector_type(4)));
typedef float f32x4  __attribute__((ext_vector_type(4)));

__device__ __forceinline__ unsigned short f2bf(float f) {
    union { float f; unsigned u; } x; x.f = f;
    unsigned u = x.u + 0x7FFFu + ((x.u >> 16) & 1u);   // RNE
    return (unsigned short)(u >> 16);
}
__device__ __forceinline__ float bf2f(unsigned short s) {
    union { unsigned u; float f; } x; x.u = ((unsigned)s) << 16;
    return x.f;
}

// ---------------- phase 1: kvT[e][d] = sum_m K[m][d] V[m][e]  (bf16) ----------------
// kT/vT layout: byte(m,col) = (m>>3)*1024 + col*16 + (m&7)*2  (subtiled, b128-friendly)
__global__ __launch_bounds__(256) void la_phase1(
    const float* __restrict__ k, const float* __restrict__ v,
    unsigned short* __restrict__ kvT, float* __restrict__ ks)
{
    const int blk = blockIdx.x;
    const int bh = blk / NC, c = blk % NC;
    const size_t rowbase = (size_t)bh * NSEQ + (size_t)c * CHUNKSZ;

    __shared__ alignas(16) unsigned short kT[CHUNKSZ * DD];
    __shared__ alignas(16) unsigned short vT[CHUNKSZ * EE];
    __shared__ float ksp[4][DD];

    char* kb = (char*)kT;
    char* vb = (char*)vT;

    const int t = threadIdx.x;
    const int w = t >> 6, l = t & 63;
    const int lg = l >> 4, lm = l & 15;
    const int col = t & 63;

    // column-pack staging: thread owns column `col`, m-groups w, w+4, w+8, w+12
    float kpart = 0.f;
#pragma unroll
    for (int pass = 0; pass < 4; ++pass) {
        const int mg = w + 4 * pass;
        const float* kp = k + (rowbase + mg * 8) * DD + col;
        const float* vp = v + (rowbase + mg * 8) * EE + col;
        float kf[8], vf[8];
#pragma unroll
        for (int j = 0; j < 8; ++j) kf[j] = kp[(size_t)j * DD];
#pragma unroll
        for (int j = 0; j < 8; ++j) vf[j] = vp[(size_t)j * EE];
        bf16x8 ku, vu;
#pragma unroll
        for (int j = 0; j < 8; ++j) {
            kpart += kf[j];
            ku[j] = (short)f2bf(kf[j]);
            vu[j] = (short)f2bf(vf[j]);
        }
        *(bf16x8*)(kb + mg * 1024 + col * 16) = ku;
        *(bf16x8*)(vb + mg * 1024 + col * 16) = vu;
    }
    ksp[w][col] = kpart;
    __syncthreads();

    // MFMA: wave w owns d-tile w, all 4 e-tiles, K=128 in 4 steps.
    f32x4 acc[4] = {};
#pragma unroll
    for (int kk = 0; kk < 4; ++kk) {
        bf16x8 aK = *(bf16x8*)(kb + (lg + 4 * kk) * 1024 + (16 * w + lm) * 16);
#pragma unroll
        for (int ei = 0; ei < 4; ++ei) {
            bf16x8 bV = *(bf16x8*)(vb + (lg + 4 * kk) * 1024 + (16 * ei + lm) * 16);
            acc[ei] = __builtin_amdgcn_mfma_f32_16x16x32_bf16(aK, bV, acc[ei], 0, 0, 0);
        }
    }
    // C-frag: row d = 16w+4lg+r, col e = 16ei+lm -> store transposed [e][d] bf16
    unsigned short* kvout = kvT + (size_t)(bh * NC + c) * DD * EE;
#pragma unroll
    for (int ei = 0; ei < 4; ++ei) {
        bf16x4 u;
        u[0] = (short)f2bf(acc[ei][0]); u[1] = (short)f2bf(acc[ei][1]);
        u[2] = (short)f2bf(acc[ei][2]); u[3] = (short)f2bf(acc[ei][3]);
        *(bf16x4*)(kvout + (16 * ei + lm) * DD + 16 * w + 4 * lg) = u;
    }
    if (t < DD)
        ks[(size_t)(bh * NC + c) * DD + t] = ksp[0][t] + ksp[1][t] + ksp[2][t] + ksp[3][t];
}

// ---------------- phase 2: exclusive prefix scan over chunks ----------------
__global__ __launch_bounds__(64) void la_phase2(
    unsigned short* __restrict__ kvT, float* __restrict__ ks, float* __restrict__ out)
{
    const int bid = blockIdx.x, t = threadIdx.x;
    if (bid < 256) {
        const int gid = bid * 64 + t;            // 0..16383
        const int bh = gid >> 9;
        const int g = gid & 511;                 // group of 8 ushorts in [e][d] tile
        unsigned short* base = kvT + (size_t)bh * (NC * DD * EE) + (size_t)g * 8;
        bf16x8 vals[NC];
#pragma unroll
        for (int c = 0; c < NC; ++c)
            vals[c] = *(const bf16x8*)(base + (size_t)c * (DD * EE));
        float run[8] = {};
#pragma unroll
        for (int c = 0; c < NC; ++c) {
            bf16x8 pr;
#pragma unroll
            for (int j = 0; j < 8; ++j) pr[j] = (short)f2bf(run[j]);
            *(bf16x8*)(base + (size_t)c * (DD * EE)) = pr;
#pragma unroll
            for (int j = 0; j < 8; ++j) run[j] += bf2f((unsigned short)vals[c][j]);
        }
        // S tail (fp32, [d][e] layout): g = e*8 + d0/8
        const int e = g >> 3, d0 = (g & 7) * 8;
        float* Sout = out + OUT0 + NBH * DD + (size_t)bh * DD * EE;
#pragma unroll
        for (int j = 0; j < 8; ++j)
            Sout[(size_t)(d0 + j) * EE + e] = run[j];
    } else {
        const int tid = (bid - 256) * 64 + t;    // 0..2047 = bh*64 + d
        const int bh = tid >> 6, d = tid & 63;
        float vals[NC];
#pragma unroll
        for (int c = 0; c < NC; ++c)
            vals[c] = ks[(size_t)(bh * NC + c) * DD + d];
        float run = 0.f;
#pragma unroll
        for (int c = 0; c < NC; ++c) {
            float x = vals[c];
            ks[(size_t)(bh * NC + c) * DD + d] = run;
            run += x;
        }
        out[OUT0 + tid] = run;                   // Z tail
    }
}

// ---------------- phase 3: per-chunk output via MFMA ----------------
// s_lds row-major [n][m] swizzled: byte(n,m) = n*256 + ((m*2) ^ ((n&7)<<4))
// k_lds row-major [m][d] swizzled: byte(m,d) = m*128 + ((d*2) ^ ((m&7)<<4))
// v_lds subtiled:  byte(m,e) = (m>>3)*1024 + e*16 + (m&7)*2
// wave w owns row-tiles ni = w and ni = 7-w (balanced causal work).
__global__ __launch_bounds__(256) void la_phase3(
    const float* __restrict__ q, const float* __restrict__ k,
    const float* __restrict__ v, const unsigned short* __restrict__ kvT,
    const float* __restrict__ ks, float* __restrict__ out)
{
    const int blk = blockIdx.x;
    const int bh = blk / NC, c = blk % NC;
    const size_t rowbase = (size_t)bh * NSEQ + (size_t)c * CHUNKSZ;

    __shared__ alignas(16) unsigned short k_lds[CHUNKSZ * DD];
    __shared__ alignas(16) unsigned short v_lds[CHUNKSZ * EE];
    __shared__ alignas(16) unsigned short s_lds[CHUNKSZ * CHUNKSZ];
    __shared__ float dinv_lds[CHUNKSZ];
    __shared__ float zi_lds[DD];

    char* kb = (char*)k_lds;
    char* vb = (char*)v_lds;
    char* sb = (char*)s_lds;

    const int t  = threadIdx.x;
    const int w  = t >> 6;
    const int l  = t & 63;
    const int lg = l >> 4;
    const int lm = l & 15;
    const int ni_of[2] = { w, 7 - w };

    // ---- staging (no s_lds zero-init) ----
    // K: row-major swizzled (8B vector writes, conflict-free)
    {
        const float4* kg = (const float4*)(k + rowbase * DD);
#pragma unroll
        for (int i = 0; i < 8; ++i) {
            int idx = t + i * 256;
            int m = idx >> 4, c4 = idx & 15;
            float4 f = kg[idx];
            bf16x4 u;
            u[0] = (short)f2bf(f.x); u[1] = (short)f2bf(f.y);
            u[2] = (short)f2bf(f.z); u[3] = (short)f2bf(f.w);
            int byt = m * 128 + ((c4 * 8) ^ ((m & 7) << 4));
            *(bf16x4*)(kb + byt) = u;
        }
    }
    // V: column-pack (conflict-free b128 writes)
    {
        const int col = t & 63;
#pragma unroll
        for (int pass = 0; pass < 4; ++pass) {
            const int mg = (t >> 6) + 4 * pass;
            const float* vp = v + (rowbase + mg * 8) * EE + col;
            float vf[8];
#pragma unroll
            for (int j = 0; j < 8; ++j) vf[j] = vp[(size_t)j * EE];
            bf16x8 u;
#pragma unroll
            for (int j = 0; j < 8; ++j) u[j] = (short)f2bf(vf[j]);
            *(bf16x8*)(vb + mg * 1024 + col * 16) = u;
        }
    }
    // state B-frags direct from global ([e][d] row-major, L2/L3-warm)
    const unsigned short* stc = kvT + (size_t)(bh * NC + c) * DD * EE;
    bf16x8 b_st[4][2];
#pragma unroll
    for (int ei = 0; ei < 4; ++ei)
#pragma unroll
        for (int kk = 0; kk < 2; ++kk)
            b_st[ei][kk] = *(const bf16x8*)(stc + (size_t)(16 * ei + lm) * DD + 8 * lg + 32 * kk);

    // Z exclusive prefix for this chunk
    if (t < DD) zi_lds[t] = ks[(size_t)(bh * NC + c) * DD + t];

    // Q A-fragments: a_q[ni2][kk], row n = 16*ni + lm, d = 8*lg + 32*kk + i
    bf16x8 a_q[2][2];
#pragma unroll
    for (int ni2 = 0; ni2 < 2; ++ni2) {
        int ni = ni_of[ni2];
        const float* qrow = q + (rowbase + 16 * ni + lm) * DD;
#pragma unroll
        for (int kk = 0; kk < 2; ++kk) {
            const float4* p = (const float4*)(qrow + 8 * lg + 32 * kk);
            float4 f0 = p[0], f1 = p[1];
            bf16x8 u;
            u[0] = (short)f2bf(f0.x); u[1] = (short)f2bf(f0.y);
            u[2] = (short)f2bf(f0.z); u[3] = (short)f2bf(f0.w);
            u[4] = (short)f2bf(f1.x); u[5] = (short)f2bf(f1.y);
            u[6] = (short)f2bf(f1.z); u[7] = (short)f2bf(f1.w);
            a_q[ni2][kk] = u;
        }
    }
    __syncthreads();

    // ---- swapped QK^T -> masked S (bf16, vector writes) + in-fragment denominator ----
#pragma unroll
    for (int ni2 = 0; ni2 < 2; ++ni2) {
        const int ni = ni_of[ni2];
        const int n = 16 * ni + lm;
        float rsum = 0.f;
        for (int mi = 0; mi <= ni; ++mi) {
            f32x4 cc = {0.f, 0.f, 0.f, 0.f};
            const int mrow = 16 * mi + lm;
#pragma unroll
            for (int kk = 0; kk < 2; ++kk) {
                int byt = mrow * 128 + (((8 * lg + 32 * kk) * 2) ^ ((mrow & 7) << 4));
                bf16x8 ak = *(bf16x8*)(kb + byt);
                // C[m-local = 4lg+r][n-local = lm]
                cc = __builtin_amdgcn_mfma_f32_16x16x32_bf16(ak, a_q[ni2][kk], cc, 0, 0, 0);
            }
            const int m0 = 16 * mi + 4 * lg;
            bf16x4 u;
#pragma unroll
            for (int r = 0; r < 4; ++r) {
                float val = (m0 + r <= n) ? cc[r] : 0.f;   // causal mask
                u[r] = (short)f2bf(val);
                rsum += val;
            }
            *(bf16x4*)(sb + n * 256 + ((m0 * 2) ^ ((n & 7) << 4))) = u;
        }
        if ((ni & 1) == 0) {                     // zero tile mi = ni+1 (read by SV)
            bf16x4 z4 = {0, 0, 0, 0};
            const int m0 = 16 * (ni + 1) + 4 * lg;
            *(bf16x4*)(sb + n * 256 + ((m0 * 2) ^ ((n & 7) << 4))) = z4;
        }
        // q . Z_prefix + eps * sum(q) for row n (from bf16 Q frags)
        float qz = 0.f, qs = 0.f;
#pragma unroll
        for (int kk = 0; kk < 2; ++kk) {
#pragma unroll
            for (int i = 0; i < 8; ++i) {
                float qf = bf2f((unsigned short)a_q[ni2][kk][i]);
                qz += qf * zi_lds[8 * lg + 32 * kk + i];
                qs += qf;
            }
        }
        float part = rsum + qz + EPSV * qs;
        part += __shfl_xor(part, 16);
        part += __shfl_xor(part, 32);
        if (lg == 0) dinv_lds[n] = 1.f / part;
    }
    __syncthreads();

    // ---- O = Q*S_state + S*V ----
    f32x4 acc[2][4];
#pragma unroll
    for (int ni2 = 0; ni2 < 2; ++ni2) {
        const int ni = ni_of[ni2];
        const int kmax = (ni >> 1) + 1;
#pragma unroll
        for (int ei = 0; ei < 4; ++ei) {
            f32x4 cc = {0.f, 0.f, 0.f, 0.f};
            const int e = 16 * ei + lm;
#pragma unroll
            for (int kk = 0; kk < 2; ++kk)   // inter: Q x S_state (B-frags in regs)
                cc = __builtin_amdgcn_mfma_f32_16x16x32_bf16(a_q[ni2][kk], b_st[ei][kk], cc, 0, 0, 0);
            const int n = 16 * ni + lm;
            for (int kk = 0; kk < kmax; ++kk) {   // intra: S x V
                int bytA = n * 256 + (((8 * lg + 32 * kk) * 2) ^ ((n & 7) << 4));
                bf16x8 as = *(bf16x8*)(sb + bytA);
                int bytB = (lg + 4 * kk) * 1024 + e * 16;
                bf16x8 bv = *(bf16x8*)(vb + bytB);
                cc = __builtin_amdgcn_mfma_f32_16x16x32_bf16(as, bv, cc, 0, 0, 0);
            }
            acc[ni2][ei] = cc;
        }
    }
    __syncthreads();

    // ---- epilogue: scale by dinv, store ----
#pragma unroll
    for (int ni2 = 0; ni2 < 2; ++ni2) {
        const int nbase = 16 * ni_of[ni2] + 4 * lg;
#pragma unroll
        for (int ei = 0; ei < 4; ++ei) {
            const int e = 16 * ei + lm;
#pragma unroll
            for (int r = 0; r < 4; ++r) {
                int n = nbase + r;
                out[(rowbase + n) * EE + e] = acc[ni2][ei][r] * dinv_lds[n];
            }
        }
    }
}

extern "C" void kernel_launch(void* const* d_in, const int* in_sizes, int n_in,
                              void* d_out, int out_size, void* d_ws, size_t ws_size,
                              hipStream_t stream)
{
    (void)in_sizes; (void)n_in; (void)out_size; (void)ws_size;
    const float* q = (const float*)d_in[0];
    const float* k = (const float*)d_in[1];
    const float* v = (const float*)d_in[2];
    float* out = (float*)d_out;
    unsigned short* kvT = (unsigned short*)d_ws;      // 8 MB bf16 per-chunk states
    float* ks = (float*)(kvT + KV_ELEMS);             // +256 KB fp32 per-chunk k-sums

    la_phase1<<<NBH * NC, 256, 0, stream>>>(k, v, kvT, ks);
    la_phase2<<<288, 64, 0, stream>>>(kvT, ks, out);
    la_phase3<<<NBH * NC, 256, 0, stream>>>(q, k, v, kvT, ks, out);
}

// Round 11
// 48.843 us; speedup vs baseline: 1.1771x; 1.0517x over previous
//
#include <hip/hip_runtime.h>

// Linear attention (chunked cumulative state), B=4 H=8 N=4096 D=E=64 CHUNK=128.
// phase1: per-chunk K^T V via bf16 MFMA + fp32 k-colsums (column-pack staging).
// phase2: register prefix scan over chunks (fp32 accum, bf16 prefixes, fp32 tails).
// phase3: per-chunk output via bf16 MFMA. Swapped QK^T; S kept ENTIRELY in
//         registers (intra-wave shfl redistribution, no s_lds, 1 barrier total);
//         LDS 33KB -> 4 blocks/CU; state B-frags direct from global.

#define CHUNKSZ 128
#define DD 64
#define EE 64
#define NC 32          // N / CHUNK
#define NBH 32         // B*H
#define NSEQ 4096
#define EPSV 1e-6f
#define OUT0 (NBH * NSEQ * EE)           // start of Z output
#define KV_ELEMS (NBH * NC * DD * EE)    // ushort count

typedef short bf16x8 __attribute__((ext_vector_type(8)));
typedef short bf16x4 __attribute__((ext_vector_type(4)));
typedef float f32x4  __attribute__((ext_vector_type(4)));

__device__ __forceinline__ unsigned short f2bf(float f) {
    union { float f; unsigned u; } x; x.f = f;
    unsigned u = x.u + 0x7FFFu + ((x.u >> 16) & 1u);   // RNE
    return (unsigned short)(u >> 16);
}
__device__ __forceinline__ float bf2f(unsigned short s) {
    union { unsigned u; float f; } x; x.u = ((unsigned)s) << 16;
    return x.f;
}

// ---------------- phase 1: kvT[e][d] = sum_m K[m][d] V[m][e]  (bf16) ----------------
__global__ __launch_bounds__(256) void la_phase1(
    const float* __restrict__ k, const float* __restrict__ v,
    unsigned short* __restrict__ kvT, float* __restrict__ ks)
{
    const int blk = blockIdx.x;
    const int bh = blk / NC, c = blk % NC;
    const size_t rowbase = (size_t)bh * NSEQ + (size_t)c * CHUNKSZ;

    __shared__ alignas(16) unsigned short kT[CHUNKSZ * DD];
    __shared__ alignas(16) unsigned short vT[CHUNKSZ * EE];
    __shared__ float ksp[4][DD];

    char* kb = (char*)kT;
    char* vb = (char*)vT;

    const int t = threadIdx.x;
    const int w = t >> 6, l = t & 63;
    const int lg = l >> 4, lm = l & 15;
    const int col = t & 63;

    float kpart = 0.f;
#pragma unroll
    for (int pass = 0; pass < 4; ++pass) {
        const int mg = w + 4 * pass;
        const float* kp = k + (rowbase + mg * 8) * DD + col;
        const float* vp = v + (rowbase + mg * 8) * EE + col;
        float kf[8], vf[8];
#pragma unroll
        for (int j = 0; j < 8; ++j) kf[j] = kp[(size_t)j * DD];
#pragma unroll
        for (int j = 0; j < 8; ++j) vf[j] = vp[(size_t)j * EE];
        bf16x8 ku, vu;
#pragma unroll
        for (int j = 0; j < 8; ++j) {
            kpart += kf[j];
            ku[j] = (short)f2bf(kf[j]);
            vu[j] = (short)f2bf(vf[j]);
        }
        *(bf16x8*)(kb + mg * 1024 + col * 16) = ku;
        *(bf16x8*)(vb + mg * 1024 + col * 16) = vu;
    }
    ksp[w][col] = kpart;
    __syncthreads();

    f32x4 acc[4] = {};
#pragma unroll
    for (int kk = 0; kk < 4; ++kk) {
        bf16x8 aK = *(bf16x8*)(kb + (lg + 4 * kk) * 1024 + (16 * w + lm) * 16);
#pragma unroll
        for (int ei = 0; ei < 4; ++ei) {
            bf16x8 bV = *(bf16x8*)(vb + (lg + 4 * kk) * 1024 + (16 * ei + lm) * 16);
            acc[ei] = __builtin_amdgcn_mfma_f32_16x16x32_bf16(aK, bV, acc[ei], 0, 0, 0);
        }
    }
    unsigned short* kvout = kvT + (size_t)(bh * NC + c) * DD * EE;
#pragma unroll
    for (int ei = 0; ei < 4; ++ei) {
        bf16x4 u;
        u[0] = (short)f2bf(acc[ei][0]); u[1] = (short)f2bf(acc[ei][1]);
        u[2] = (short)f2bf(acc[ei][2]); u[3] = (short)f2bf(acc[ei][3]);
        *(bf16x4*)(kvout + (16 * ei + lm) * DD + 16 * w + 4 * lg) = u;
    }
    if (t < DD)
        ks[(size_t)(bh * NC + c) * DD + t] = ksp[0][t] + ksp[1][t] + ksp[2][t] + ksp[3][t];
}

// ---------------- phase 2: exclusive prefix scan over chunks ----------------
__global__ __launch_bounds__(64) void la_phase2(
    unsigned short* __restrict__ kvT, float* __restrict__ ks, float* __restrict__ out)
{
    const int bid = blockIdx.x, t = threadIdx.x;
    if (bid < 256) {
        const int gid = bid * 64 + t;            // 0..16383
        const int bh = gid >> 9;
        const int g = gid & 511;                 // group of 8 ushorts in [e][d] tile
        unsigned short* base = kvT + (size_t)bh * (NC * DD * EE) + (size_t)g * 8;
        bf16x8 vals[NC];
#pragma unroll
        for (int c = 0; c < NC; ++c)
            vals[c] = *(const bf16x8*)(base + (size_t)c * (DD * EE));
        float run[8] = {};
#pragma unroll
        for (int c = 0; c < NC; ++c) {
            bf16x8 pr;
#pragma unroll
            for (int j = 0; j < 8; ++j) pr[j] = (short)f2bf(run[j]);
            *(bf16x8*)(base + (size_t)c * (DD * EE)) = pr;
#pragma unroll
            for (int j = 0; j < 8; ++j) run[j] += bf2f((unsigned short)vals[c][j]);
        }
        const int e = g >> 3, d0 = (g & 7) * 8;
        float* Sout = out + OUT0 + NBH * DD + (size_t)bh * DD * EE;
#pragma unroll
        for (int j = 0; j < 8; ++j)
            Sout[(size_t)(d0 + j) * EE + e] = run[j];
    } else {
        const int tid = (bid - 256) * 64 + t;    // 0..2047 = bh*64 + d
        const int bh = tid >> 6, d = tid & 63;
        float vals[NC];
#pragma unroll
        for (int c = 0; c < NC; ++c)
            vals[c] = ks[(size_t)(bh * NC + c) * DD + d];
        float run = 0.f;
#pragma unroll
        for (int c = 0; c < NC; ++c) {
            float x = vals[c];
            ks[(size_t)(bh * NC + c) * DD + d] = run;
            run += x;
        }
        out[OUT0 + tid] = run;                   // Z tail
    }
}

// ---------------- phase 3: per-chunk output, S fully in registers ----------------
// k_lds row-major [m][d] swizzled: byte(m,d) = m*128 + ((d*2) ^ ((m&7)<<4))
// v_lds subtiled:  byte(m,e) = (m>>3)*1024 + e*16 + (m&7)*2
// wave w owns row-tiles ni = w and ni = 7-w (balanced causal work).
// S redistribution: source lane (lg_s,lm) holds S[16mi+4lg_s+r][16ni+lm]; target
// A-frag word j of block kk comes from tile mi=2kk+(lg>>1), src lane 2(lg&1)+(j>>1),
// lo/hi pair = j&1. 4 shfls per tile, select by parity.
__global__ __launch_bounds__(256) void la_phase3(
    const float* __restrict__ q, const float* __restrict__ k,
    const float* __restrict__ v, const unsigned short* __restrict__ kvT,
    const float* __restrict__ ks, float* __restrict__ out)
{
    const int blk = blockIdx.x;
    const int bh = blk / NC, c = blk % NC;
    const size_t rowbase = (size_t)bh * NSEQ + (size_t)c * CHUNKSZ;

    __shared__ alignas(16) unsigned short k_lds[CHUNKSZ * DD];   // 16 KB
    __shared__ alignas(16) unsigned short v_lds[CHUNKSZ * EE];   // 16 KB
    __shared__ float zi_lds[DD];

    char* kb = (char*)k_lds;
    char* vb = (char*)v_lds;

    const int t  = threadIdx.x;
    const int w  = t >> 6;
    const int l  = t & 63;
    const int lg = l >> 4;
    const int lm = l & 15;

    // ---- staging ----
    // K: row-major swizzled (8B vector writes, conflict-free)
    {
        const float4* kg = (const float4*)(k + rowbase * DD);
#pragma unroll
        for (int i = 0; i < 8; ++i) {
            int idx = t + i * 256;
            int m = idx >> 4, c4 = idx & 15;
            float4 f = kg[idx];
            bf16x4 u;
            u[0] = (short)f2bf(f.x); u[1] = (short)f2bf(f.y);
            u[2] = (short)f2bf(f.z); u[3] = (short)f2bf(f.w);
            int byt = m * 128 + ((c4 * 8) ^ ((m & 7) << 4));
            *(bf16x4*)(kb + byt) = u;
        }
    }
    // V: column-pack (conflict-free b128 writes)
    {
        const int col = t & 63;
#pragma unroll
        for (int pass = 0; pass < 4; ++pass) {
            const int mg = (t >> 6) + 4 * pass;
            const float* vp = v + (rowbase + mg * 8) * EE + col;
            float vf[8];
#pragma unroll
            for (int j = 0; j < 8; ++j) vf[j] = vp[(size_t)j * EE];
            bf16x8 u;
#pragma unroll
            for (int j = 0; j < 8; ++j) u[j] = (short)f2bf(vf[j]);
            *(bf16x8*)(vb + mg * 1024 + col * 16) = u;
        }
    }
    // state B-frags direct from global ([e][d] row-major, L2/L3-warm)
    const unsigned short* stc = kvT + (size_t)(bh * NC + c) * DD * EE;
    bf16x8 b_st[4][2];
#pragma unroll
    for (int ei = 0; ei < 4; ++ei)
#pragma unroll
        for (int kk = 0; kk < 2; ++kk)
            b_st[ei][kk] = *(const bf16x8*)(stc + (size_t)(16 * ei + lm) * DD + 8 * lg + 32 * kk);

    // Z exclusive prefix for this chunk
    if (t < DD) zi_lds[t] = ks[(size_t)(bh * NC + c) * DD + t];
    __syncthreads();      // the ONLY barrier

    const int src1 = 32 * (lg & 1) + lm;
    const int src2 = src1 + 16;
    const int par  = lg >> 1;

#pragma unroll
    for (int ni2 = 0; ni2 < 2; ++ni2) {
        const int ni = ni2 ? (7 - w) : w;
        const int n = 16 * ni + lm;
        const int kmax = (ni >> 1) + 1;

        // Q A-frags for this ni
        bf16x8 aq[2];
        {
            const float* qrow = q + (rowbase + n) * DD;
#pragma unroll
            for (int kk = 0; kk < 2; ++kk) {
                const float4* p = (const float4*)(qrow + 8 * lg + 32 * kk);
                float4 f0 = p[0], f1 = p[1];
                bf16x8 u;
                u[0] = (short)f2bf(f0.x); u[1] = (short)f2bf(f0.y);
                u[2] = (short)f2bf(f0.z); u[3] = (short)f2bf(f0.w);
                u[4] = (short)f2bf(f1.x); u[5] = (short)f2bf(f1.y);
                u[6] = (short)f2bf(f1.z); u[7] = (short)f2bf(f1.w);
                aq[kk] = u;
            }
        }

        // S A-frag words (zero-init covers the ragged causal edge)
        unsigned a_s[4][4];
#pragma unroll
        for (int b = 0; b < 4; ++b) {
            a_s[b][0] = 0; a_s[b][1] = 0; a_s[b][2] = 0; a_s[b][3] = 0;
        }

        // swapped QK^T tiles -> mask -> pack -> intra-wave redistribute
        float rsum = 0.f;
#pragma unroll
        for (int mi = 0; mi < 8; ++mi) {
            if (mi <= ni) {                       // wave-uniform
                f32x4 cc = {0.f, 0.f, 0.f, 0.f};
                const int mrow = 16 * mi + lm;
#pragma unroll
                for (int kk = 0; kk < 2; ++kk) {
                    int byt = mrow * 128 + (((8 * lg + 32 * kk) * 2) ^ ((mrow & 7) << 4));
                    bf16x8 ak = *(bf16x8*)(kb + byt);
                    cc = __builtin_amdgcn_mfma_f32_16x16x32_bf16(ak, aq[kk], cc, 0, 0, 0);
                }
                const int m0 = 16 * mi + 4 * lg;
                float v0 = (m0 + 0 <= n) ? cc[0] : 0.f;
                float v1 = (m0 + 1 <= n) ? cc[1] : 0.f;
                float v2 = (m0 + 2 <= n) ? cc[2] : 0.f;
                float v3 = (m0 + 3 <= n) ? cc[3] : 0.f;
                rsum += (v0 + v1) + (v2 + v3);
                unsigned p_lo = (unsigned)f2bf(v0) | ((unsigned)f2bf(v1) << 16);
                unsigned p_hi = (unsigned)f2bf(v2) | ((unsigned)f2bf(v3) << 16);
                unsigned w0 = (unsigned)__shfl((int)p_lo, src1);
                unsigned w1 = (unsigned)__shfl((int)p_hi, src1);
                unsigned w2 = (unsigned)__shfl((int)p_lo, src2);
                unsigned w3 = (unsigned)__shfl((int)p_hi, src2);
                const bool take = (par == (mi & 1));
                const int b = mi >> 1;
                a_s[b][0] = take ? w0 : a_s[b][0];
                a_s[b][1] = take ? w1 : a_s[b][1];
                a_s[b][2] = take ? w2 : a_s[b][2];
                a_s[b][3] = take ? w3 : a_s[b][3];
            }
        }

        // denominator: rsum + q.Z + eps*sum(q), reduced across the 4 lg lanes
        float qz = 0.f, qs = 0.f;
#pragma unroll
        for (int kk = 0; kk < 2; ++kk) {
#pragma unroll
            for (int i = 0; i < 8; ++i) {
                float qf = bf2f((unsigned short)aq[kk][i]);
                qz += qf * zi_lds[8 * lg + 32 * kk + i];
                qs += qf;
            }
        }
        float part = rsum + qz + EPSV * qs;
        part += __shfl_xor(part, 16);
        part += __shfl_xor(part, 32);
        const float dinv = 1.f / part;            // every lane: row 16ni+lm

        // O = Q x S_state + S x V
        f32x4 acc[4];
#pragma unroll
        for (int ei = 0; ei < 4; ++ei) {
            f32x4 cc = {0.f, 0.f, 0.f, 0.f};
            const int e = 16 * ei + lm;
            cc = __builtin_amdgcn_mfma_f32_16x16x32_bf16(aq[0], b_st[ei][0], cc, 0, 0, 0);
            cc = __builtin_amdgcn_mfma_f32_16x16x32_bf16(aq[1], b_st[ei][1], cc, 0, 0, 0);
#pragma unroll
            for (int kk = 0; kk < 4; ++kk) {
                if (kk < kmax) {                  // wave-uniform
                    union { unsigned u[4]; bf16x8 f; } as;
                    as.u[0] = a_s[kk][0]; as.u[1] = a_s[kk][1];
                    as.u[2] = a_s[kk][2]; as.u[3] = a_s[kk][3];
                    int bytB = (lg + 4 * kk) * 1024 + e * 16;
                    bf16x8 bv = *(bf16x8*)(vb + bytB);
                    cc = __builtin_amdgcn_mfma_f32_16x16x32_bf16(as.f, bv, cc, 0, 0, 0);
                }
            }
            acc[ei] = cc;
        }

        // epilogue: dinv for row 16ni+4lg+r lives at lane (lg=0, lm=4lg+r)
#pragma unroll
        for (int r = 0; r < 4; ++r) {
            float dr = __shfl(dinv, 4 * lg + r);
            const int nr = 16 * ni + 4 * lg + r;
            float* orow = out + (rowbase + nr) * EE + lm;
#pragma unroll
            for (int ei = 0; ei < 4; ++ei)
                orow[16 * ei] = acc[ei][r] * dr;
        }
    }
}

extern "C" void kernel_launch(void* const* d_in, const int* in_sizes, int n_in,
                              void* d_out, int out_size, void* d_ws, size_t ws_size,
                              hipStream_t stream)
{
    (void)in_sizes; (void)n_in; (void)out_size; (void)ws_size;
    const float* q = (const float*)d_in[0];
    const float* k = (const float*)d_in[1];
    const float* v = (const float*)d_in[2];
    float* out = (float*)d_out;
    unsigned short* kvT = (unsigned short*)d_ws;      // 8 MB bf16 per-chunk states
    float* ks = (float*)(kvT + KV_ELEMS);             // +256 KB fp32 per-chunk k-sums

    la_phase1<<<NBH * NC, 256, 0, stream>>>(k, v, kvT, ks);
    la_phase2<<<288, 64, 0, stream>>>(kvT, ks, out);
    la_phase3<<<NBH * NC, 256, 0, stream>>>(q, k, v, kvT, ks, out);
}